// Round 4
// baseline (906.899 us; speedup 1.0000x reference)
//
#include <hip/hip_runtime.h>
#include <hip/hip_bf16.h>
#include <stdint.h>

#define M_DIM 8192
#define K_DIM 4096
#define N_DIM 11008
#define NKT   (K_DIM / 64)   // 64 K-tiles of 64
#define NIT   (NKT / 2)      // 32 iterations, 2 K-tiles each

typedef __attribute__((ext_vector_type(8))) short bf16x8;
typedef __attribute__((ext_vector_type(4))) float f32x4;
typedef __attribute__((ext_vector_type(4))) unsigned int uint4v;

__device__ __forceinline__ unsigned short f2bf(float f) {
    __hip_bfloat16 h = __float2bfloat16(f);
    return __builtin_bit_cast(unsigned short, h);
}

__device__ __forceinline__ void gload_lds16(const unsigned short* g, unsigned short* l) {
    __builtin_amdgcn_global_load_lds(
        (const __attribute__((address_space(1))) void*)g,
        (__attribute__((address_space(3))) void*)l,
        16, 0, 0);
}

__device__ __forceinline__ unsigned lds_addr(const unsigned short* p) {
    return (unsigned)(uintptr_t)(const __attribute__((address_space(3))) unsigned short*)p;
}

// inline-asm ds_read_b128: invisible to the compiler's LDS dependency tracker,
// so no auto-inserted vmcnt(0) drains — the hand-placed counted waits rule.
#define DSR(dst, a, OFF) asm volatile("ds_read_b128 %0, %1 offset:" OFF \
    : "=v"(dst) : "v"(a) : "memory")

__device__ __forceinline__ void ld_quad(bf16x8* d, unsigned a) {
    DSR(d[0], a, "0");
    DSR(d[1], a, "1024");
    DSR(d[2], a, "2048");
    DSR(d[3], a, "3072");
}

// ---------------------------------------------------------------------------
// Kernel 1: fused column-gather + fp32->bf16 convert for a chunk of M rows.
// ---------------------------------------------------------------------------
__global__ void permute_x_kernel(const float* __restrict__ x,
                                 const int* __restrict__ ci,
                                 unsigned short* __restrict__ xg) {
    int idx = blockIdx.x * 256 + threadIdx.x;
    int64_t base = (int64_t)idx * 4;
    int m = (int)(base >> 12);        // K=4096
    int k = (int)(base & 4095);
    const float* xrow = x + ((int64_t)m << 12);
    int4 c4 = *reinterpret_cast<const int4*>(ci + k);
    ushort4 o;
    o.x = f2bf(xrow[c4.x]);
    o.y = f2bf(xrow[c4.y]);
    o.z = f2bf(xrow[c4.z]);
    o.w = f2bf(xrow[c4.w]);
    *reinterpret_cast<ushort4*>(xg + base) = o;
}

// ---------------------------------------------------------------------------
// Kernel 2: int4 unpack + per-group scale + transpose to wT[N][K] bf16.
// ---------------------------------------------------------------------------
__global__ void dequant_w_kernel(const int* __restrict__ wp,
                                 const float* __restrict__ scales,
                                 unsigned short* __restrict__ wT) {
    __shared__ unsigned short tile[64][65];
    int n0 = blockIdx.x * 64;
    int k0 = blockIdx.y * 64;
    int g = k0 >> 7;
    int t = threadIdx.x;
    int col = t & 63;
    int r0 = t >> 6;
    float s = scales[(int64_t)g * N_DIM + n0 + col];
    int pr0 = k0 >> 1;
#pragma unroll
    for (int i = 0; i < 8; ++i) {
        int row = r0 + i * 4;
        int p = wp[(int64_t)(pr0 + row) * N_DIM + n0 + col];
        tile[2 * row][col]     = f2bf((float)((p & 15) - 8) * s);
        tile[2 * row + 1][col] = f2bf((float)(((p >> 4) & 15) - 8) * s);
    }
    __syncthreads();
    int nl = t >> 2;
    int kk0 = (t & 3) << 4;
    unsigned short vals[16];
#pragma unroll
    for (int j = 0; j < 16; ++j) vals[j] = tile[kk0 + j][nl];
    uint4v* dst = reinterpret_cast<uint4v*>(wT + (int64_t)(n0 + nl) * K_DIM + k0 + kk0);
    dst[0] = *reinterpret_cast<const uint4v*>(&vals[0]);
    dst[1] = *reinterpret_cast<const uint4v*>(&vals[8]);
}

// ---------------------------------------------------------------------------
// Kernel 3: bf16 GEMM, 256x256 tile, 8-phase schedule (T3+T4+T5), asm ds_read.
// LDS 128 KiB = 2 buffers x {A_k0, A_k1, B_k0, B_k1}, each region
// [256 rows][32 k] bf16 (16 KiB, 64B rows -> fragment reads cover a
// contiguous 1 KiB per wave = conflict-free).
// Byte offsets: buf*65536 + isB*32768 + kk*16384; frag row stride 1024 B.
//
// Phase table (iteration it; tiles T0=2it in buf0, T1=2it+1 in buf1):
//  ph1: read buf0.A_k0 m0-3 + buf0.B_k0      | stage buf1.A_k1 <- 2it+1
//  ph2: read buf0.A_k0 m4-7 + buf0.A_k1 m0-3 | stage buf0.B_k0 <- 2it+2
//  ph3: read buf0.A_k1 m4-7 + buf0.B_k1      | stage buf0.A_k0 <- 2it+2
//  ph4: (no reads)                           | stage buf0.B_k1 <- 2it+2 | vmcnt(6)
//  ph5: read buf1.A_k0 m0-3 + buf1.B_k0      | stage buf0.A_k1 <- 2it+2
//  ph6: read buf1.A_k0 m4-7 + buf1.A_k1 m0-3 | stage buf1.B_k0 <- 2it+3
//  ph7: read buf1.A_k1 m4-7 + buf1.B_k1      | stage buf1.A_k0 <- 2it+3
//  ph8: (no reads)                           | stage buf1.B_k1 <- 2it+3 | vmcnt(6)
// Every region's overwrite is issued >=1 barrier after its last read; the
// per-wave vmcnt(6) immediately before a barrier gives the cross-wave
// landing guarantee (each wave drains its own 8 oldest loads = one buf).
// ---------------------------------------------------------------------------

template <int MB>
__device__ __forceinline__ void mfma_blk(f32x4 (&acc)[8][4], const bf16x8 (&av)[8],
                                         const bf16x8 (&bv)[4]) {
    __builtin_amdgcn_s_setprio(1);
#pragma unroll
    for (int m = 0; m < 4; ++m)
#pragma unroll
        for (int n = 0; n < 4; ++n)
            acc[MB + m][n] = __builtin_amdgcn_mfma_f32_16x16x32_bf16(
                av[MB + m], bv[n], acc[MB + m][n], 0, 0, 0);
    __builtin_amdgcn_s_setprio(0);
}

// stage one 16 KiB region (256 rows x 32 k) of tile kt: 2 gload_lds per wave.
template <int BUF, int ISB, int KK>
__device__ __forceinline__ void stage(const unsigned short* __restrict__ G, int row0,
                                      int kt, unsigned short* lds,
                                      int w32, int riw, int s8, int wLds) {
    if (kt < NKT) {
#pragma unroll
        for (int j = 0; j < 2; ++j) {
            const unsigned short* src =
                G + (int64_t)(row0 + w32 + j * 16 + riw) * K_DIM + kt * 64 + KK * 32 + s8;
            gload_lds16(src, lds + BUF * 32768 + ISB * 16384 + KK * 8192 + wLds + j * 512);
        }
    }
}

#define BAR() do { __builtin_amdgcn_s_barrier(); asm volatile("" ::: "memory"); } while (0)
// barrier, then drain this wave's ds_reads, then fence the scheduler so the
// MFMAs (register-only) cannot hoist above the wait (guide rule #18).
#define PHASE_SYNC() do { \
    __builtin_amdgcn_s_barrier(); \
    asm volatile("s_waitcnt lgkmcnt(0)" ::: "memory"); \
    __builtin_amdgcn_sched_barrier(0); \
} while (0)

__global__ __launch_bounds__(512, 2)
void gemm_kernel(const unsigned short* __restrict__ A,
                 const unsigned short* __restrict__ BT,
                 const float* __restrict__ bias,
                 float* __restrict__ C) {
    __shared__ unsigned short lds[65536];   // 128 KiB

    constexpr int NT = N_DIM / 256;  // 43
    int wg = blockIdx.x, nwg = gridDim.x;
    int q = nwg >> 3, r = nwg & 7;
    int xcd = wg & 7, li = wg >> 3;
    int swz = (xcd < r ? xcd * (q + 1) : r * (q + 1) + (xcd - r) * q) + li;
    int by = swz / NT, bx = swz - by * NT;
    int brow = by << 8, bcol = bx << 8;

    int t = threadIdx.x;
    int lane = t & 63, w = t >> 6;
    int wr = w >> 2, wc = w & 3;           // 2 x 4 wave grid
    int fr = lane & 15, fq = lane >> 4;

    const int aBase = (wr * 128 + fr) * 32 + fq * 8;   // elements
    const int bBase = (wc * 64 + fr) * 32 + fq * 8;    // elements
    const int riw = lane >> 2, s8 = (lane & 3) << 3;
    const int w32 = w * 32, wLds = w * 1024;

    // LDS byte addresses for asm ds_read (buf1 = +65536 B, beyond the 16-bit
    // offset immediate, so it gets its own base VGPR).
    const unsigned aA0 = lds_addr(lds + aBase);
    const unsigned bA0 = lds_addr(lds + 16384 + bBase);
    const unsigned aA1 = aA0 + 65536;
    const unsigned bA1 = bA0 + 65536;

    f32x4 acc[8][4];
#pragma unroll
    for (int m = 0; m < 8; ++m)
#pragma unroll
        for (int n = 0; n < 4; ++n) acc[m][n] = (f32x4){0.f, 0.f, 0.f, 0.f};

    // ---- prologue: buf0 <- tile0 (4 regions = 8 loads), buf1 <- tile1
    // {B_k0, A_k0, B_k1} (6 loads). vmcnt(6) -> buf0 fully landed.
    stage<0, 0, 0>(A,  brow, 0, lds, w32, riw, s8, wLds);   // buf0.A_k0
    stage<0, 0, 1>(A,  brow, 0, lds, w32, riw, s8, wLds);   // buf0.A_k1
    stage<0, 1, 0>(BT, bcol, 0, lds, w32, riw, s8, wLds);   // buf0.B_k0
    stage<0, 1, 1>(BT, bcol, 0, lds, w32, riw, s8, wLds);   // buf0.B_k1
    stage<1, 1, 0>(BT, bcol, 1, lds, w32, riw, s8, wLds);   // buf1.B_k0
    stage<1, 0, 0>(A,  brow, 1, lds, w32, riw, s8, wLds);   // buf1.A_k0
    stage<1, 1, 1>(BT, bcol, 1, lds, w32, riw, s8, wLds);   // buf1.B_k1
    asm volatile("s_waitcnt vmcnt(6)" ::: "memory");
    BAR();

#pragma unroll 1
    for (int it = 0; it < NIT; ++it) {
        const int t1 = 2 * it + 1, t2 = 2 * it + 2, t3 = 2 * it + 3;
        const bool lastIt = (it == NIT - 1);
        bf16x8 a0[8], a1[8], b0[4], b1[4];

        // ---------------- phase 1 ----------------
        ld_quad(&a0[0], aA0);                 // buf0.A_k0 m0-3
        ld_quad(&b0[0], bA0);                 // buf0.B_k0
        stage<1, 0, 1>(A, brow, t1, lds, w32, riw, s8, wLds);   // buf1.A_k1 <- t1
        PHASE_SYNC();
        mfma_blk<0>(acc, a0, b0);
        BAR();

        // ---------------- phase 2 ----------------
        ld_quad(&a0[4], aA0 + 4096);          // buf0.A_k0 m4-7
        ld_quad(&a1[0], aA0 + 16384);         // buf0.A_k1 m0-3
        stage<0, 1, 0>(BT, bcol, t2, lds, w32, riw, s8, wLds);  // buf0.B_k0 <- t2
        PHASE_SYNC();
        mfma_blk<4>(acc, a0, b0);
        BAR();

        // ---------------- phase 3 ----------------
        ld_quad(&a1[4], aA0 + 20480);         // buf0.A_k1 m4-7
        ld_quad(&b1[0], bA0 + 16384);         // buf0.B_k1
        stage<0, 0, 0>(A, brow, t2, lds, w32, riw, s8, wLds);   // buf0.A_k0 <- t2
        PHASE_SYNC();
        mfma_blk<0>(acc, a1, b1);
        BAR();

        // ---------------- phase 4 ----------------
        stage<0, 1, 1>(BT, bcol, t2, lds, w32, riw, s8, wLds);  // buf0.B_k1 <- t2
        PHASE_SYNC();
        mfma_blk<4>(acc, a1, b1);
        if (!lastIt) asm volatile("s_waitcnt vmcnt(6)" ::: "memory");
        else         asm volatile("s_waitcnt vmcnt(0)" ::: "memory");
        BAR();

        // ---------------- phase 5 ----------------
        ld_quad(&a0[0], aA1);                 // buf1.A_k0 m0-3
        ld_quad(&b0[0], bA1);                 // buf1.B_k0
        stage<0, 0, 1>(A, brow, t2, lds, w32, riw, s8, wLds);   // buf0.A_k1 <- t2
        PHASE_SYNC();
        mfma_blk<0>(acc, a0, b0);
        BAR();

        // ---------------- phase 6 ----------------
        ld_quad(&a0[4], aA1 + 4096);          // buf1.A_k0 m4-7
        ld_quad(&a1[0], aA1 + 16384);         // buf1.A_k1 m0-3
        stage<1, 1, 0>(BT, bcol, t3, lds, w32, riw, s8, wLds);  // buf1.B_k0 <- t3
        PHASE_SYNC();
        mfma_blk<4>(acc, a0, b0);
        BAR();

        // ---------------- phase 7 ----------------
        ld_quad(&a1[4], aA1 + 20480);         // buf1.A_k1 m4-7
        ld_quad(&b1[0], bA1 + 16384);         // buf1.B_k1
        stage<1, 0, 0>(A, brow, t3, lds, w32, riw, s8, wLds);   // buf1.A_k0 <- t3
        PHASE_SYNC();
        mfma_blk<0>(acc, a1, b1);
        BAR();

        // ---------------- phase 8 ----------------
        stage<1, 1, 1>(BT, bcol, t3, lds, w32, riw, s8, wLds);  // buf1.B_k1 <- t3
        PHASE_SYNC();
        mfma_blk<4>(acc, a1, b1);
        if (!lastIt) asm volatile("s_waitcnt vmcnt(6)" ::: "memory");
        BAR();
    }

    // ---- epilogue: C/D layout col=lane&15, row=(lane>>4)*4+reg ----
    int orow0 = brow + wr * 128 + fq * 4;
    int ocol0 = bcol + wc * 64 + fr;
#pragma unroll
    for (int n = 0; n < 4; ++n) {
        int col = ocol0 + n * 16;
        float bval = bias[col];
#pragma unroll
        for (int m = 0; m < 8; ++m) {
            int row = orow0 + m * 16;
            float* cp = C + (int64_t)row * N_DIM + col;
#pragma unroll
            for (int j = 0; j < 4; ++j) {
                cp[(int64_t)j * N_DIM] = acc[m][n][j] + bval;
            }
        }
    }
}

extern "C" void kernel_launch(void* const* d_in, const int* in_sizes, int n_in,
                              void* d_out, int out_size, void* d_ws, size_t ws_size,
                              hipStream_t stream) {
    const float* x      = (const float*)d_in[0];
    const int* ci       = (const int*)d_in[1];
    const int* wp       = (const int*)d_in[2];
    const float* scales = (const float*)d_in[3];
    const float* bias   = (const float*)d_in[4];
    float* out          = (float*)d_out;

    // workspace: wT bf16 [N,K] (86 MiB) first, then xg chunk (fit to ws_size).
    const size_t wT_bytes = (size_t)N_DIM * K_DIM * 2;
    unsigned short* wT = (unsigned short*)d_ws;
    unsigned short* xg = wT + (size_t)N_DIM * K_DIM;

    size_t cap = (ws_size > wT_bytes) ? (ws_size - wT_bytes) : 0;
    int max_rows = (int)(cap / ((size_t)K_DIM * 2));
    int chunk_rows = (max_rows / 256) * 256;
    if (chunk_rows <= 0) chunk_rows = 256;      // best effort
    if (chunk_rows > M_DIM) chunk_rows = M_DIM;

    dequant_w_kernel<<<dim3(N_DIM / 64, K_DIM / 64), 256, 0, stream>>>(wp, scales, wT);

    for (int m0 = 0; m0 < M_DIM; m0 += chunk_rows) {
        int rows = M_DIM - m0 < chunk_rows ? M_DIM - m0 : chunk_rows;
        int pgrid = (int)(((int64_t)rows * K_DIM) / (4 * 256));
        permute_x_kernel<<<pgrid, 256, 0, stream>>>(
            x + (int64_t)m0 * K_DIM, ci, xg);
        int grid = (rows / 256) * (N_DIM / 256);
        gemm_kernel<<<grid, 512, 0, stream>>>(
            xg, wT, bias, out + (int64_t)m0 * N_DIM);
    }
}

// Round 5
// 864.770 us; speedup vs baseline: 1.0487x; 1.0487x over previous
//
#include <hip/hip_runtime.h>
#include <hip/hip_bf16.h>
#include <stdint.h>

#define M_DIM 8192
#define K_DIM 4096
#define N_DIM 11008
#define NKT   (K_DIM / 64)   // 64 K-tiles of 64
#define NIT   (NKT / 2)      // 32 iterations, 2 K-tiles each

typedef __attribute__((ext_vector_type(8))) short bf16x8;
typedef __attribute__((ext_vector_type(4))) float f32x4;
typedef __attribute__((ext_vector_type(4))) unsigned int uint4v;

__device__ __forceinline__ unsigned short f2bf(float f) {
    __hip_bfloat16 h = __float2bfloat16(f);
    return __builtin_bit_cast(unsigned short, h);
}

__device__ __forceinline__ void gload_lds16(const unsigned short* g, unsigned short* l) {
    __builtin_amdgcn_global_load_lds(
        (const __attribute__((address_space(1))) void*)g,
        (__attribute__((address_space(3))) void*)l,
        16, 0, 0);
}

__device__ __forceinline__ unsigned lds_addr(const unsigned short* p) {
    return (unsigned)(uintptr_t)(const __attribute__((address_space(3))) unsigned short*)p;
}

// inline-asm ds_read_b128: invisible to the compiler's LDS dependency tracker,
// so no auto-inserted vmcnt(0) drains — the hand-placed counted waits rule.
#define DSR(dst, a, OFF) asm volatile("ds_read_b128 %0, %1 offset:" OFF \
    : "=v"(dst) : "v"(a) : "memory")

__device__ __forceinline__ void ld_quad(bf16x8* d, unsigned a) {
    DSR(d[0], a, "0");
    DSR(d[1], a, "1024");
    DSR(d[2], a, "2048");
    DSR(d[3], a, "3072");
}

// ---------------------------------------------------------------------------
// Kernel 1: fused column-gather + fp32->bf16 convert for a chunk of M rows.
// ---------------------------------------------------------------------------
__global__ void permute_x_kernel(const float* __restrict__ x,
                                 const int* __restrict__ ci,
                                 unsigned short* __restrict__ xg) {
    int idx = blockIdx.x * 256 + threadIdx.x;
    int64_t base = (int64_t)idx * 4;
    int m = (int)(base >> 12);        // K=4096
    int k = (int)(base & 4095);
    const float* xrow = x + ((int64_t)m << 12);
    int4 c4 = *reinterpret_cast<const int4*>(ci + k);
    ushort4 o;
    o.x = f2bf(xrow[c4.x]);
    o.y = f2bf(xrow[c4.y]);
    o.z = f2bf(xrow[c4.z]);
    o.w = f2bf(xrow[c4.w]);
    *reinterpret_cast<ushort4*>(xg + base) = o;
}

// ---------------------------------------------------------------------------
// Kernel 2: int4 unpack + per-group scale + transpose to wT[N][K] bf16.
// ---------------------------------------------------------------------------
__global__ void dequant_w_kernel(const int* __restrict__ wp,
                                 const float* __restrict__ scales,
                                 unsigned short* __restrict__ wT) {
    __shared__ unsigned short tile[64][65];
    int n0 = blockIdx.x * 64;
    int k0 = blockIdx.y * 64;
    int g = k0 >> 7;
    int t = threadIdx.x;
    int col = t & 63;
    int r0 = t >> 6;
    float s = scales[(int64_t)g * N_DIM + n0 + col];
    int pr0 = k0 >> 1;
#pragma unroll
    for (int i = 0; i < 8; ++i) {
        int row = r0 + i * 4;
        int p = wp[(int64_t)(pr0 + row) * N_DIM + n0 + col];
        tile[2 * row][col]     = f2bf((float)((p & 15) - 8) * s);
        tile[2 * row + 1][col] = f2bf((float)(((p >> 4) & 15) - 8) * s);
    }
    __syncthreads();
    int nl = t >> 2;
    int kk0 = (t & 3) << 4;
    unsigned short vals[16];
#pragma unroll
    for (int j = 0; j < 16; ++j) vals[j] = tile[kk0 + j][nl];
    uint4v* dst = reinterpret_cast<uint4v*>(wT + (int64_t)(n0 + nl) * K_DIM + k0 + kk0);
    dst[0] = *reinterpret_cast<const uint4v*>(&vals[0]);
    dst[1] = *reinterpret_cast<const uint4v*>(&vals[8]);
}

// ---------------------------------------------------------------------------
// Kernel 3: bf16 GEMM, 256x256 tile, 8-phase schedule (T3+T4+T5), asm ds_read,
// T2 bank-conflict XOR swizzle.
// LDS 128 KiB = 2 buffers x {A_k0, A_k1, B_k0, B_k1}, each region
// [256 rows][32 k] bf16 (16 KiB, 64B rows).
//
// Swizzle (T2): physical_byte = linear_byte ^ ((row&6)<<3). ds_read_b128
// serves 8-lane groups (8 x 16B = one 32-bank sweep); linear 64B rows give
// banks (fr*16)&127 -> fr aliases fr+2 (4-way conflict, the round-3/4
// 6.8e7-conflict signal). XORing row bits[2:1] into byte bits[5:4] makes
// each 8-lane group cover all 32 banks. Both-sides-or-neither (rule #21):
// global_load_lds dest stays lane-linear; the SOURCE column is permuted by
// the same involution: col_elems = ((lane&3) ^ ((lane>>3)&3)) << 3
// (w- and j-terms vanish mod 4). Read side: XOR value is (fr&6)<<3 for both
// A (row=wr*128+fr) and B (row=wc*64+fr) -> folded into base VGPRs; all
// offset: immediates are multiples of 1024 so the XOR commutes with them.
//
// Phase table (iteration it; tiles T0=2it in buf0, T1=2it+1 in buf1):
//  ph1: read buf0.A_k0 m0-3 + buf0.B_k0      | stage buf1.A_k1 <- 2it+1
//  ph2: read buf0.A_k0 m4-7 + buf0.A_k1 m0-3 | stage buf0.B_k0 <- 2it+2
//  ph3: read buf0.A_k1 m4-7 + buf0.B_k1      | stage buf0.A_k0 <- 2it+2
//  ph4: (no reads)                           | stage buf0.B_k1 <- 2it+2 | vmcnt(6)
//  ph5: read buf1.A_k0 m0-3 + buf1.B_k0      | stage buf0.A_k1 <- 2it+2
//  ph6: read buf1.A_k0 m4-7 + buf1.A_k1 m0-3 | stage buf1.B_k0 <- 2it+3
//  ph7: read buf1.A_k1 m4-7 + buf1.B_k1      | stage buf1.A_k0 <- 2it+3
//  ph8: (no reads)                           | stage buf1.B_k1 <- 2it+3 | vmcnt(6)
// ph4's vmcnt(6) leaves ph2/3/4 stages outstanding -> buf1(t1) landed before
// ph5 reads it; ph8's vmcnt(6) leaves ph6/7/8 -> buf0(t2) landed before next
// iteration's ph1. Every region's overwrite is issued >=1 barrier after its
// last read.
// ---------------------------------------------------------------------------

template <int MB>
__device__ __forceinline__ void mfma_blk(f32x4 (&acc)[8][4], const bf16x8 (&av)[8],
                                         const bf16x8 (&bv)[4]) {
    __builtin_amdgcn_s_setprio(1);
#pragma unroll
    for (int m = 0; m < 4; ++m)
#pragma unroll
        for (int n = 0; n < 4; ++n)
            acc[MB + m][n] = __builtin_amdgcn_mfma_f32_16x16x32_bf16(
                av[MB + m], bv[n], acc[MB + m][n], 0, 0, 0);
    __builtin_amdgcn_s_setprio(0);
}

// stage one 16 KiB region (256 rows x 32 k) of tile kt: 2 gload_lds per wave.
// s8 carries the T2 source-column permutation.
template <int BUF, int ISB, int KK>
__device__ __forceinline__ void stage(const unsigned short* __restrict__ G, int row0,
                                      int kt, unsigned short* lds,
                                      int w32, int riw, int s8, int wLds) {
    if (kt < NKT) {
#pragma unroll
        for (int j = 0; j < 2; ++j) {
            const unsigned short* src =
                G + (int64_t)(row0 + w32 + j * 16 + riw) * K_DIM + kt * 64 + KK * 32 + s8;
            gload_lds16(src, lds + BUF * 32768 + ISB * 16384 + KK * 8192 + wLds + j * 512);
        }
    }
}

#define BAR() do { __builtin_amdgcn_s_barrier(); asm volatile("" ::: "memory"); } while (0)
// barrier, then drain this wave's ds_reads, then fence the scheduler so the
// MFMAs (register-only) cannot hoist above the wait (guide rule #18).
#define PHASE_SYNC() do { \
    __builtin_amdgcn_s_barrier(); \
    asm volatile("s_waitcnt lgkmcnt(0)" ::: "memory"); \
    __builtin_amdgcn_sched_barrier(0); \
} while (0)

__global__ __launch_bounds__(512, 2)
void gemm_kernel(const unsigned short* __restrict__ A,
                 const unsigned short* __restrict__ BT,
                 const float* __restrict__ bias,
                 float* __restrict__ C) {
    __shared__ unsigned short lds[65536];   // 128 KiB

    constexpr int NT = N_DIM / 256;  // 43
    int wg = blockIdx.x, nwg = gridDim.x;
    int q = nwg >> 3, r = nwg & 7;
    int xcd = wg & 7, li = wg >> 3;
    int swz = (xcd < r ? xcd * (q + 1) : r * (q + 1) + (xcd - r) * q) + li;
    int by = swz / NT, bx = swz - by * NT;
    int brow = by << 8, bcol = bx << 8;

    int t = threadIdx.x;
    int lane = t & 63, w = t >> 6;
    int wr = w >> 2, wc = w & 3;           // 2 x 4 wave grid
    int fr = lane & 15, fq = lane >> 4;

    // T2: per-lane bank-swizzle XOR (constant across all regions/offsets)
    const unsigned xr = (unsigned)((fr & 6) << 3);

    const int riw = lane >> 2;
    // T2 source-column permutation (elements): ((lane&3) ^ ((lane>>3)&3)) * 8
    const int s8 = ((lane & 3) ^ ((lane >> 3) & 3)) << 3;
    const int w32 = w * 32, wLds = w * 1024;

    // LDS byte addresses for asm ds_read (buf1 = +65536 B, beyond the 16-bit
    // offset immediate, so it gets its own base VGPR). XOR applied once here.
    const unsigned aA0 = (lds_addr(lds) + (unsigned)((wr * 128 + fr) * 64 + fq * 16)) ^ xr;
    const unsigned bA0 = (lds_addr(lds) + 32768u + (unsigned)((wc * 64 + fr) * 64 + fq * 16)) ^ xr;
    const unsigned aA1 = aA0 + 65536;
    const unsigned bA1 = bA0 + 65536;

    f32x4 acc[8][4];
#pragma unroll
    for (int m = 0; m < 8; ++m)
#pragma unroll
        for (int n = 0; n < 4; ++n) acc[m][n] = (f32x4){0.f, 0.f, 0.f, 0.f};

    // ---- prologue: buf0 <- tile0 (4 regions = 8 loads), buf1 <- tile1
    // {B_k0, A_k0, B_k1} (6 loads). vmcnt(6) -> buf0 fully landed.
    stage<0, 0, 0>(A,  brow, 0, lds, w32, riw, s8, wLds);   // buf0.A_k0
    stage<0, 0, 1>(A,  brow, 0, lds, w32, riw, s8, wLds);   // buf0.A_k1
    stage<0, 1, 0>(BT, bcol, 0, lds, w32, riw, s8, wLds);   // buf0.B_k0
    stage<0, 1, 1>(BT, bcol, 0, lds, w32, riw, s8, wLds);   // buf0.B_k1
    stage<1, 1, 0>(BT, bcol, 1, lds, w32, riw, s8, wLds);   // buf1.B_k0
    stage<1, 0, 0>(A,  brow, 1, lds, w32, riw, s8, wLds);   // buf1.A_k0
    stage<1, 1, 1>(BT, bcol, 1, lds, w32, riw, s8, wLds);   // buf1.B_k1
    asm volatile("s_waitcnt vmcnt(6)" ::: "memory");
    BAR();

#pragma unroll 1
    for (int it = 0; it < NIT; ++it) {
        const int t1 = 2 * it + 1, t2 = 2 * it + 2, t3 = 2 * it + 3;
        const bool lastIt = (it == NIT - 1);
        bf16x8 a0[8], a1[8], b0[4], b1[4];

        // ---------------- phase 1 ----------------
        ld_quad(&a0[0], aA0);                 // buf0.A_k0 m0-3
        ld_quad(&b0[0], bA0);                 // buf0.B_k0
        stage<1, 0, 1>(A, brow, t1, lds, w32, riw, s8, wLds);   // buf1.A_k1 <- t1
        PHASE_SYNC();
        mfma_blk<0>(acc, a0, b0);
        BAR();

        // ---------------- phase 2 ----------------
        ld_quad(&a0[4], aA0 + 4096);          // buf0.A_k0 m4-7
        ld_quad(&a1[0], aA0 + 16384);         // buf0.A_k1 m0-3
        stage<0, 1, 0>(BT, bcol, t2, lds, w32, riw, s8, wLds);  // buf0.B_k0 <- t2
        PHASE_SYNC();
        mfma_blk<4>(acc, a0, b0);
        BAR();

        // ---------------- phase 3 ----------------
        ld_quad(&a1[4], aA0 + 20480);         // buf0.A_k1 m4-7
        ld_quad(&b1[0], bA0 + 16384);         // buf0.B_k1
        stage<0, 0, 0>(A, brow, t2, lds, w32, riw, s8, wLds);   // buf0.A_k0 <- t2
        PHASE_SYNC();
        mfma_blk<0>(acc, a1, b1);
        BAR();

        // ---------------- phase 4 ----------------
        stage<0, 1, 1>(BT, bcol, t2, lds, w32, riw, s8, wLds);  // buf0.B_k1 <- t2
        PHASE_SYNC();
        mfma_blk<4>(acc, a1, b1);
        if (!lastIt) asm volatile("s_waitcnt vmcnt(6)" ::: "memory");
        else         asm volatile("s_waitcnt vmcnt(0)" ::: "memory");
        BAR();

        // ---------------- phase 5 ----------------
        ld_quad(&a0[0], aA1);                 // buf1.A_k0 m0-3
        ld_quad(&b0[0], bA1);                 // buf1.B_k0
        stage<0, 0, 1>(A, brow, t2, lds, w32, riw, s8, wLds);   // buf0.A_k1 <- t2
        PHASE_SYNC();
        mfma_blk<0>(acc, a0, b0);
        BAR();

        // ---------------- phase 6 ----------------
        ld_quad(&a0[4], aA1 + 4096);          // buf1.A_k0 m4-7
        ld_quad(&a1[0], aA1 + 16384);         // buf1.A_k1 m0-3
        stage<1, 1, 0>(BT, bcol, t3, lds, w32, riw, s8, wLds);  // buf1.B_k0 <- t3
        PHASE_SYNC();
        mfma_blk<4>(acc, a0, b0);
        BAR();

        // ---------------- phase 7 ----------------
        ld_quad(&a1[4], aA1 + 20480);         // buf1.A_k1 m4-7
        ld_quad(&b1[0], bA1 + 16384);         // buf1.B_k1
        stage<1, 0, 0>(A, brow, t3, lds, w32, riw, s8, wLds);   // buf1.A_k0 <- t3
        PHASE_SYNC();
        mfma_blk<0>(acc, a1, b1);
        BAR();

        // ---------------- phase 8 ----------------
        stage<1, 1, 1>(BT, bcol, t3, lds, w32, riw, s8, wLds);  // buf1.B_k1 <- t3
        PHASE_SYNC();
        mfma_blk<4>(acc, a1, b1);
        if (!lastIt) asm volatile("s_waitcnt vmcnt(6)" ::: "memory");
        BAR();
    }

    // ---- epilogue: C/D layout col=lane&15, row=(lane>>4)*4+reg ----
    int orow0 = brow + wr * 128 + fq * 4;
    int ocol0 = bcol + wc * 64 + fr;
#pragma unroll
    for (int n = 0; n < 4; ++n) {
        int col = ocol0 + n * 16;
        float bval = bias[col];
#pragma unroll
        for (int m = 0; m < 8; ++m) {
            int row = orow0 + m * 16;
            float* cp = C + (int64_t)row * N_DIM + col;
#pragma unroll
            for (int j = 0; j < 4; ++j) {
                cp[(int64_t)j * N_DIM] = acc[m][n][j] + bval;
            }
        }
    }
}

extern "C" void kernel_launch(void* const* d_in, const int* in_sizes, int n_in,
                              void* d_out, int out_size, void* d_ws, size_t ws_size,
                              hipStream_t stream) {
    const float* x      = (const float*)d_in[0];
    const int* ci       = (const int*)d_in[1];
    const int* wp       = (const int*)d_in[2];
    const float* scales = (const float*)d_in[3];
    const float* bias   = (const float*)d_in[4];
    float* out          = (float*)d_out;

    // workspace: wT bf16 [N,K] (86 MiB) first, then xg chunk (fit to ws_size).
    const size_t wT_bytes = (size_t)N_DIM * K_DIM * 2;
    unsigned short* wT = (unsigned short*)d_ws;
    unsigned short* xg = wT + (size_t)N_DIM * K_DIM;

    size_t cap = (ws_size > wT_bytes) ? (ws_size - wT_bytes) : 0;
    int max_rows = (int)(cap / ((size_t)K_DIM * 2));
    int chunk_rows = (max_rows / 256) * 256;
    if (chunk_rows <= 0) chunk_rows = 256;      // best effort
    if (chunk_rows > M_DIM) chunk_rows = M_DIM;

    dequant_w_kernel<<<dim3(N_DIM / 64, K_DIM / 64), 256, 0, stream>>>(wp, scales, wT);

    for (int m0 = 0; m0 < M_DIM; m0 += chunk_rows) {
        int rows = M_DIM - m0 < chunk_rows ? M_DIM - m0 : chunk_rows;
        int pgrid = (int)(((int64_t)rows * K_DIM) / (4 * 256));
        permute_x_kernel<<<pgrid, 256, 0, stream>>>(
            x + (int64_t)m0 * K_DIM, ci, xg);
        int grid = (rows / 256) * (N_DIM / 256);
        gemm_kernel<<<grid, 512, 0, stream>>>(
            xg, wT, bias, out + (int64_t)m0 * N_DIM);
    }
}

// Round 6
// 847.595 us; speedup vs baseline: 1.0700x; 1.0203x over previous
//
#include <hip/hip_runtime.h>
#include <hip/hip_bf16.h>
#include <stdint.h>

#define M_DIM 8192
#define K_DIM 4096
#define N_DIM 11008
#define NKT   (K_DIM / 64)   // 64 K-tiles of 64
#define NIT   (NKT / 2)      // 32 iterations, 2 K-tiles each

typedef __attribute__((ext_vector_type(8))) short bf16x8;
typedef __attribute__((ext_vector_type(4))) float f32x4;
typedef __attribute__((ext_vector_type(4))) unsigned int uint4v;

__device__ __forceinline__ unsigned short f2bf(float f) {
    __hip_bfloat16 h = __float2bfloat16(f);
    return __builtin_bit_cast(unsigned short, h);
}

__device__ __forceinline__ void gload_lds16(const unsigned short* g, unsigned short* l) {
    __builtin_amdgcn_global_load_lds(
        (const __attribute__((address_space(1))) void*)g,
        (__attribute__((address_space(3))) void*)l,
        16, 0, 0);
}

__device__ __forceinline__ unsigned lds_addr(const unsigned short* p) {
    return (unsigned)(uintptr_t)(const __attribute__((address_space(3))) unsigned short*)p;
}

// inline-asm ds_read_b128: invisible to the compiler's LDS dependency tracker;
// only the hand-placed counted lgkm waits order the consumers.
#define DSR(dst, a, OFF) asm volatile("ds_read_b128 %0, %1 offset:" OFF \
    : "=v"(dst) : "v"(a) : "memory")

__device__ __forceinline__ void ld_quad(bf16x8* d, unsigned a) {
    DSR(d[0], a, "0");
    DSR(d[1], a, "1024");
    DSR(d[2], a, "2048");
    DSR(d[3], a, "3072");
}

// ---------------------------------------------------------------------------
// Kernel 1: fused column-gather + fp32->bf16 convert.
// ---------------------------------------------------------------------------
__global__ void permute_x_kernel(const float* __restrict__ x,
                                 const int* __restrict__ ci,
                                 unsigned short* __restrict__ xg) {
    int idx = blockIdx.x * 256 + threadIdx.x;
    int64_t base = (int64_t)idx * 4;
    int m = (int)(base >> 12);        // K=4096
    int k = (int)(base & 4095);
    const float* xrow = x + ((int64_t)m << 12);
    int4 c4 = *reinterpret_cast<const int4*>(ci + k);
    ushort4 o;
    o.x = f2bf(xrow[c4.x]);
    o.y = f2bf(xrow[c4.y]);
    o.z = f2bf(xrow[c4.z]);
    o.w = f2bf(xrow[c4.w]);
    *reinterpret_cast<ushort4*>(xg + base) = o;
}

// ---------------------------------------------------------------------------
// Kernel 2: int4 unpack + per-group scale + transpose to wT[N][K] bf16.
// ---------------------------------------------------------------------------
__global__ void dequant_w_kernel(const int* __restrict__ wp,
                                 const float* __restrict__ scales,
                                 unsigned short* __restrict__ wT) {
    __shared__ unsigned short tile[64][65];
    int n0 = blockIdx.x * 64;
    int k0 = blockIdx.y * 64;
    int g = k0 >> 7;
    int t = threadIdx.x;
    int col = t & 63;
    int r0 = t >> 6;
    float s = scales[(int64_t)g * N_DIM + n0 + col];
    int pr0 = k0 >> 1;
#pragma unroll
    for (int i = 0; i < 8; ++i) {
        int row = r0 + i * 4;
        int p = wp[(int64_t)(pr0 + row) * N_DIM + n0 + col];
        tile[2 * row][col]     = f2bf((float)((p & 15) - 8) * s);
        tile[2 * row + 1][col] = f2bf((float)(((p >> 4) & 15) - 8) * s);
    }
    __syncthreads();
    int nl = t >> 2;
    int kk0 = (t & 3) << 4;
    unsigned short vals[16];
#pragma unroll
    for (int j = 0; j < 16; ++j) vals[j] = tile[kk0 + j][nl];
    uint4v* dst = reinterpret_cast<uint4v*>(wT + (int64_t)(n0 + nl) * K_DIM + k0 + kk0);
    dst[0] = *reinterpret_cast<const uint4v*>(&vals[0]);
    dst[1] = *reinterpret_cast<const uint4v*>(&vals[8]);
}

// ---------------------------------------------------------------------------
// Kernel 3: bf16 GEMM, 256x256 tile, 8-phase schedule, asm ds_read, T2
// swizzle, and ONE-PHASE-AHEAD register loads (this round's change).
//
// Stall model (round-5 post-mortem): reads->lgkm(0)->MFMA serialized because
// the wave stalls at MFMA issue (shallow matrix-pipe queue), so next-phase
// reads couldn't start until MFMAs drained. Fix: issue phase p+1's ds_reads
// BEFORE phase p's MFMA cluster; wait with counted lgkmcnt (DS returns are
// in-order per wave) so only the needed frags gate the MFMAs.
//
// Read schedule (R-sets of 8 ds_read_b128):
//  ph1: issue R1{a0 m0-3,b0}+R2{a0 m4-7,a1 m0-3} (buf0)   lgkm(8): R1 ready
//  ph2: issue R3{a1 m4-7,b1} (buf0)                        lgkm(8): R2 ready
//  ph3: (no reads)                                         lgkm(0): R3 ready
//  ph4: (no reads; MFMA uses R3 frags)                     vmcnt(6)
//  ph5: issue R5+R6 (buf1 mirror of R1+R2)                 lgkm(8): R5 ready
//  ph6: issue R7 (buf1 mirror of R3)                       lgkm(8): R6 ready
//  ph7: (no reads)                                         lgkm(0): R7 ready
//  ph8: (no reads)                                         vmcnt(6)
//
// Stage placement, vmcnt(6) at ph4/ph8, and barrier structure are identical
// to round 5. Overwrite-safety re-derived: every stage of region R lands
// >=1 full barrier after the lgkm wait covering R's last reads:
//   buf0.B_k0<-t2 @ph2 (b0 read R1, covered ph1 lgkm(8), BAR1)        OK
//   buf0.A_k0<-t2 @ph3 (a0 read R1/R2, covered ph2 lgkm(8), BAR2)     OK
//   buf0.B_k1<-t2 @ph4 (b1 read R3, covered ph3 lgkm(0), BAR3)        OK
//   buf0.A_k1<-t2 @ph5 (a1 read R2/R3, covered ph3 lgkm(0), BAR3)     OK
//   buf1.A_k1<-t1 @ph1 (prev R7, covered prev ph7 lgkm(0), BAR7')     OK
//   buf1.B_k0<-t3 @ph6 (b0' read R5, covered ph5 lgkm(8), BAR5)       OK
//   buf1.A_k0<-t3 @ph7 (a0' read R5/R6, covered ph6 lgkm(8), BAR6)    OK
//   buf1.B_k1<-t3 @ph8 (b1' read R7, covered ph7 lgkm(0), BAR7)       OK
// ---------------------------------------------------------------------------

template <int MB>
__device__ __forceinline__ void mfma_blk(f32x4 (&acc)[8][4], const bf16x8 (&av)[8],
                                         const bf16x8 (&bv)[4]) {
    __builtin_amdgcn_s_setprio(1);
#pragma unroll
    for (int m = 0; m < 4; ++m)
#pragma unroll
        for (int n = 0; n < 4; ++n)
            acc[MB + m][n] = __builtin_amdgcn_mfma_f32_16x16x32_bf16(
                av[MB + m], bv[n], acc[MB + m][n], 0, 0, 0);
    __builtin_amdgcn_s_setprio(0);
}

// stage one 16 KiB region (256 rows x 32 k) of tile kt: 2 gload_lds per wave.
// s8 carries the T2 source-column permutation (inverse of the read swizzle).
template <int BUF, int ISB, int KK>
__device__ __forceinline__ void stage(const unsigned short* __restrict__ G, int row0,
                                      int kt, unsigned short* lds,
                                      int w32, int riw, int s8, int wLds) {
    if (kt < NKT) {
#pragma unroll
        for (int j = 0; j < 2; ++j) {
            const unsigned short* src =
                G + (int64_t)(row0 + w32 + j * 16 + riw) * K_DIM + kt * 64 + KK * 32 + s8;
            gload_lds16(src, lds + BUF * 32768 + ISB * 16384 + KK * 8192 + wLds + j * 512);
        }
    }
}

#define BAR() do { __builtin_amdgcn_s_barrier(); asm volatile("" ::: "memory"); } while (0)
// counted lgkm wait + scheduler fence (rule #18: register-only MFMAs would
// otherwise hoist above the wait despite the memory clobber).
#define LGKM(N) do { \
    asm volatile("s_waitcnt lgkmcnt(" #N ")" ::: "memory"); \
    __builtin_amdgcn_sched_barrier(0); \
} while (0)

__global__ __launch_bounds__(512, 2)
void gemm_kernel(const unsigned short* __restrict__ A,
                 const unsigned short* __restrict__ BT,
                 const float* __restrict__ bias,
                 float* __restrict__ C) {
    __shared__ unsigned short lds[65536];   // 128 KiB

    constexpr int NT = N_DIM / 256;  // 43
    int wg = blockIdx.x, nwg = gridDim.x;
    int q = nwg >> 3, r = nwg & 7;
    int xcd = wg & 7, li = wg >> 3;
    int swz = (xcd < r ? xcd * (q + 1) : r * (q + 1) + (xcd - r) * q) + li;
    int by = swz / NT, bx = swz - by * NT;
    int brow = by << 8, bcol = bx << 8;

    int t = threadIdx.x;
    int lane = t & 63, w = t >> 6;
    int wr = w >> 2, wc = w & 3;           // 2 x 4 wave grid
    int fr = lane & 15, fq = lane >> 4;

    // T2: per-lane bank-swizzle XOR (constant across all regions/offsets)
    const unsigned xr = (unsigned)((fr & 6) << 3);

    const int riw = lane >> 2;
    // T2 source-column permutation (elements): ((lane&3) ^ ((lane>>3)&3)) * 8
    const int s8 = ((lane & 3) ^ ((lane >> 3) & 3)) << 3;
    const int w32 = w * 32, wLds = w * 1024;

    const unsigned aA0 = (lds_addr(lds) + (unsigned)((wr * 128 + fr) * 64 + fq * 16)) ^ xr;
    const unsigned bA0 = (lds_addr(lds) + 32768u + (unsigned)((wc * 64 + fr) * 64 + fq * 16)) ^ xr;
    const unsigned aA1 = aA0 + 65536;
    const unsigned bA1 = bA0 + 65536;

    f32x4 acc[8][4];
#pragma unroll
    for (int m = 0; m < 8; ++m)
#pragma unroll
        for (int n = 0; n < 4; ++n) acc[m][n] = (f32x4){0.f, 0.f, 0.f, 0.f};

    // ---- prologue: buf0 <- tile0 (4 regions = 8 loads), buf1 <- tile1
    // {B_k0, A_k0, B_k1} (6 loads). vmcnt(6) -> buf0 fully landed.
    stage<0, 0, 0>(A,  brow, 0, lds, w32, riw, s8, wLds);   // buf0.A_k0
    stage<0, 0, 1>(A,  brow, 0, lds, w32, riw, s8, wLds);   // buf0.A_k1
    stage<0, 1, 0>(BT, bcol, 0, lds, w32, riw, s8, wLds);   // buf0.B_k0
    stage<0, 1, 1>(BT, bcol, 0, lds, w32, riw, s8, wLds);   // buf0.B_k1
    stage<1, 1, 0>(BT, bcol, 1, lds, w32, riw, s8, wLds);   // buf1.B_k0
    stage<1, 0, 0>(A,  brow, 1, lds, w32, riw, s8, wLds);   // buf1.A_k0
    stage<1, 1, 1>(BT, bcol, 1, lds, w32, riw, s8, wLds);   // buf1.B_k1
    asm volatile("s_waitcnt vmcnt(6)" ::: "memory");
    BAR();

#pragma unroll 1
    for (int it = 0; it < NIT; ++it) {
        const int t1 = 2 * it + 1, t2 = 2 * it + 2, t3 = 2 * it + 3;
        const bool lastIt = (it == NIT - 1);
        bf16x8 a0[8], a1[8], b0[4], b1[4];

        // ---------------- phase 1 ----------------
        ld_quad(&a0[0], aA0);                 // R1: buf0.A_k0 m0-3
        ld_quad(&b0[0], bA0);                 // R1: buf0.B_k0
        ld_quad(&a0[4], aA0 + 4096);          // R2: buf0.A_k0 m4-7
        ld_quad(&a1[0], aA0 + 16384);         // R2: buf0.A_k1 m0-3
        stage<1, 0, 1>(A, brow, t1, lds, w32, riw, s8, wLds);   // buf1.A_k1 <- t1
        LGKM(8);                              // R1 ready; R2 drains under MFMA
        mfma_blk<0>(acc, a0, b0);
        BAR();

        // ---------------- phase 2 ----------------
        ld_quad(&a1[4], aA0 + 20480);         // R3: buf0.A_k1 m4-7
        ld_quad(&b1[0], bA0 + 16384);         // R3: buf0.B_k1
        stage<0, 1, 0>(BT, bcol, t2, lds, w32, riw, s8, wLds);  // buf0.B_k0 <- t2
        LGKM(8);                              // R2 ready; R3 drains under MFMA
        mfma_blk<4>(acc, a0, b0);
        BAR();

        // ---------------- phase 3 ----------------
        stage<0, 0, 0>(A, brow, t2, lds, w32, riw, s8, wLds);   // buf0.A_k0 <- t2
        LGKM(0);                              // R3 ready
        mfma_blk<0>(acc, a1, b1);
        BAR();

        // ---------------- phase 4 ----------------
        stage<0, 1, 1>(BT, bcol, t2, lds, w32, riw, s8, wLds);  // buf0.B_k1 <- t2
        mfma_blk<4>(acc, a1, b1);             // operands R3: ready since ph3
        if (!lastIt) asm volatile("s_waitcnt vmcnt(6)" ::: "memory");
        else         asm volatile("s_waitcnt vmcnt(0)" ::: "memory");
        BAR();                                // publishes buf1 (tile t1)

        // ---------------- phase 5 ----------------
        ld_quad(&a0[0], aA1);                 // R5: buf1.A_k0 m0-3
        ld_quad(&b0[0], bA1);                 // R5: buf1.B_k0
        ld_quad(&a0[4], aA1 + 4096);          // R6: buf1.A_k0 m4-7
        ld_quad(&a1[0], aA1 + 16384);         // R6: buf1.A_k1 m0-3
        stage<0, 0, 1>(A, brow, t2, lds, w32, riw, s8, wLds);   // buf0.A_k1 <- t2
        LGKM(8);                              // R5 ready
        mfma_blk<0>(acc, a0, b0);
        BAR();

        // ---------------- phase 6 ----------------
        ld_quad(&a1[4], aA1 + 20480);         // R7: buf1.A_k1 m4-7
        ld_quad(&b1[0], bA1 + 16384);         // R7: buf1.B_k1
        stage<1, 1, 0>(BT, bcol, t3, lds, w32, riw, s8, wLds);  // buf1.B_k0 <- t3
        LGKM(8);                              // R6 ready
        mfma_blk<4>(acc, a0, b0);
        BAR();

        // ---------------- phase 7 ----------------
        stage<1, 0, 0>(A, brow, t3, lds, w32, riw, s8, wLds);   // buf1.A_k0 <- t3
        LGKM(0);                              // R7 ready
        mfma_blk<0>(acc, a1, b1);
        BAR();

        // ---------------- phase 8 ----------------
        stage<1, 1, 1>(BT, bcol, t3, lds, w32, riw, s8, wLds);  // buf1.B_k1 <- t3
        mfma_blk<4>(acc, a1, b1);             // operands R7: ready since ph7
        if (!lastIt) asm volatile("s_waitcnt vmcnt(6)" ::: "memory");
        BAR();                                // publishes buf0 (tile t2)
    }

    // ---- epilogue: C/D layout col=lane&15, row=(lane>>4)*4+reg ----
    int orow0 = brow + wr * 128 + fq * 4;
    int ocol0 = bcol + wc * 64 + fr;
#pragma unroll
    for (int n = 0; n < 4; ++n) {
        int col = ocol0 + n * 16;
        float bval = bias[col];
#pragma unroll
        for (int m = 0; m < 8; ++m) {
            int row = orow0 + m * 16;
            float* cp = C + (int64_t)row * N_DIM + col;
#pragma unroll
            for (int j = 0; j < 4; ++j) {
                cp[(int64_t)j * N_DIM] = acc[m][n][j] + bval;
            }
        }
    }
}

extern "C" void kernel_launch(void* const* d_in, const int* in_sizes, int n_in,
                              void* d_out, int out_size, void* d_ws, size_t ws_size,
                              hipStream_t stream) {
    const float* x      = (const float*)d_in[0];
    const int* ci       = (const int*)d_in[1];
    const int* wp       = (const int*)d_in[2];
    const float* scales = (const float*)d_in[3];
    const float* bias   = (const float*)d_in[4];
    float* out          = (float*)d_out;

    const size_t wT_bytes = (size_t)N_DIM * K_DIM * 2;
    unsigned short* wT = (unsigned short*)d_ws;
    unsigned short* xg = wT + (size_t)N_DIM * K_DIM;

    size_t cap = (ws_size > wT_bytes) ? (ws_size - wT_bytes) : 0;
    int max_rows = (int)(cap / ((size_t)K_DIM * 2));
    int chunk_rows = (max_rows / 256) * 256;
    if (chunk_rows <= 0) chunk_rows = 256;      // best effort
    if (chunk_rows > M_DIM) chunk_rows = M_DIM;

    dequant_w_kernel<<<dim3(N_DIM / 64, K_DIM / 64), 256, 0, stream>>>(wp, scales, wT);

    for (int m0 = 0; m0 < M_DIM; m0 += chunk_rows) {
        int rows = M_DIM - m0 < chunk_rows ? M_DIM - m0 : chunk_rows;
        int pgrid = (int)(((int64_t)rows * K_DIM) / (4 * 256));
        permute_x_kernel<<<pgrid, 256, 0, stream>>>(
            x + (int64_t)m0 * K_DIM, ci, xg);
        int grid = (rows / 256) * (N_DIM / 256);
        gemm_kernel<<<grid, 512, 0, stream>>>(
            xg, wT, bias, out + (int64_t)m0 * N_DIM);
    }
}

// Round 7
// 833.734 us; speedup vs baseline: 1.0878x; 1.0166x over previous
//
#include <hip/hip_runtime.h>
#include <hip/hip_bf16.h>
#include <stdint.h>

#define M_DIM 8192
#define K_DIM 4096
#define N_DIM 11008
#define NT32  128            // K-tiles of 32

typedef __attribute__((ext_vector_type(8))) short bf16x8;
typedef __attribute__((ext_vector_type(4))) float f32x4;
typedef __attribute__((ext_vector_type(4))) unsigned int uint4v;

__device__ __forceinline__ unsigned short f2bf(float f) {
    __hip_bfloat16 h = __float2bfloat16(f);
    return __builtin_bit_cast(unsigned short, h);
}

__device__ __forceinline__ void gload_lds16(const unsigned short* g, unsigned short* l) {
    __builtin_amdgcn_global_load_lds(
        (const __attribute__((address_space(1))) void*)g,
        (__attribute__((address_space(3))) void*)l,
        16, 0, 0);
}

__device__ __forceinline__ unsigned lds_addr(const unsigned short* p) {
    return (unsigned)(uintptr_t)(const __attribute__((address_space(3))) unsigned short*)p;
}

// inline-asm ds_read_b128 with immediate offset ("n" constraint so templated
// constexpr offsets fold into the offset: field). Invisible to the compiler's
// LDS dependency tracker; hand-placed counted lgkm waits order the consumers.
#define DSRI(dst, a, OFF) asm volatile("ds_read_b128 %0, %1 offset:%2" \
    : "=v"(dst) : "v"(a), "n"(OFF) : "memory")

// counted lgkm wait + scheduler fence (rule #18).
#define LGKM(N) do { \
    asm volatile("s_waitcnt lgkmcnt(" #N ")" ::: "memory"); \
    __builtin_amdgcn_sched_barrier(0); \
} while (0)
#define BAR() do { __builtin_amdgcn_s_barrier(); asm volatile("" ::: "memory"); } while (0)

// ---------------------------------------------------------------------------
// Kernel 1: fused column-gather + fp32->bf16 convert.
// ---------------------------------------------------------------------------
__global__ void permute_x_kernel(const float* __restrict__ x,
                                 const int* __restrict__ ci,
                                 unsigned short* __restrict__ xg) {
    int idx = blockIdx.x * 256 + threadIdx.x;
    int64_t base = (int64_t)idx * 4;
    int m = (int)(base >> 12);        // K=4096
    int k = (int)(base & 4095);
    const float* xrow = x + ((int64_t)m << 12);
    int4 c4 = *reinterpret_cast<const int4*>(ci + k);
    ushort4 o;
    o.x = f2bf(xrow[c4.x]);
    o.y = f2bf(xrow[c4.y]);
    o.z = f2bf(xrow[c4.z]);
    o.w = f2bf(xrow[c4.w]);
    *reinterpret_cast<ushort4*>(xg + base) = o;
}

// ---------------------------------------------------------------------------
// Kernel 2: int4 unpack + per-group scale + transpose to wT[N][K] bf16.
// ---------------------------------------------------------------------------
__global__ void dequant_w_kernel(const int* __restrict__ wp,
                                 const float* __restrict__ scales,
                                 unsigned short* __restrict__ wT) {
    __shared__ unsigned short tile[64][65];
    int n0 = blockIdx.x * 64;
    int k0 = blockIdx.y * 64;
    int g = k0 >> 7;
    int t = threadIdx.x;
    int col = t & 63;
    int r0 = t >> 6;
    float s = scales[(int64_t)g * N_DIM + n0 + col];
    int pr0 = k0 >> 1;
#pragma unroll
    for (int i = 0; i < 8; ++i) {
        int row = r0 + i * 4;
        int p = wp[(int64_t)(pr0 + row) * N_DIM + n0 + col];
        tile[2 * row][col]     = f2bf((float)((p & 15) - 8) * s);
        tile[2 * row + 1][col] = f2bf((float)(((p >> 4) & 15) - 8) * s);
    }
    __syncthreads();
    int nl = t >> 2;
    int kk0 = (t & 3) << 4;
    unsigned short vals[16];
#pragma unroll
    for (int j = 0; j < 16; ++j) vals[j] = tile[kk0 + j][nl];
    uint4v* dst = reinterpret_cast<uint4v*>(wT + (int64_t)(n0 + nl) * K_DIM + k0 + kk0);
    dst[0] = *reinterpret_cast<const uint4v*>(&vals[0]);
    dst[1] = *reinterpret_cast<const uint4v*>(&vals[8]);
}

// ---------------------------------------------------------------------------
// Kernel 3: bf16 GEMM, 256x256 tile, 3-BUFFER ROTATION (BK=32, this round).
//
// LDS 96 KiB = 3 bufs x {A [256 rows][32 k] 16 KiB, B [256 rows][32 k] 16 KiB}.
// Byte map: buf k -> A @ k*32768, B @ k*32768+16384. T2 XOR swizzle as r5:
// phys = lin ^ ((row&6)<<3); staging source col perm s8 unchanged.
//
// Per K-tile j (buf B=j%3): 2 phases.
//  P1: issue RB_j (4 ds_read: a m4-7 of buf B); stage A_{j+2}->buf (B+2)%3;
//      LGKM(4) [drains RA_j, issued one phase earlier]; 16 MFMA (rows 0-3);
//      vmcnt(2); BAR.
//  P2: issue RA_{j+1} (8 ds_read: a m0-3 + b n0-3 of buf (B+1)%3);
//      stage B_{j+2}; LGKM(8) [drains RB_j]; 16 MFMA (rows 4-7); BAR.
//
// Why 3 buffers: with 2 buffers the first cluster after a buffer publish
// cannot have its reads pre-issued (publish barrier = issue barrier) ->
// ~500-cyc all-wave read-burst stall at ph1/ph5 (round-6 diagnosis). With
// rotation, buf j+1 is published (vmcnt(2)+BAR at P1(j)) before P2(j)
// issues RA_{j+1}: every cluster's operands are issued a full phase ahead.
//
// vmcnt(2) ledger (induction, 2 loads per stage call): after P1(j)'s
// vmcnt(2) the only outstanding stages are A_{j+2}; P2(j-1) had added
// B_{j+1}, P1(j) added A_{j+2}; vmcnt(2) drains A_{j+1},B_{j+1} -> buf_{j+1}
// confirmed before its reads. Stage->confirm >= 1.3 phases (~1700 cyc) >
// 900-cyc HBM-miss latency.
//
// Overwrite ledger: stage A->buf (j+2)%3 == (j-1)%3: its A-region last read
// by RB_{j-1} (issued P1(j-1), covered LGKM(8)@P2(j-1), barrier after) ->
// stage at P1(j) is >=1 barrier later. Stage B: last read RA_{j-1} (issued
// P2(j-2), covered LGKM(4)@P1(j-1)) -> >=2 barriers. OK.
//
// Loop: 21 statically-unrolled 6-tile bodies (bufs 0,1,2,0,1,2 and frag
// 2-coloring X,Y alternating — all compile-time, rule #20), tail tiles
// 126/127 peeled (no stages; vmcnt(0) at T126-P1).
// ---------------------------------------------------------------------------

template <int BUF>
__device__ __forceinline__ void read_RA(bf16x8 (&a)[4], bf16x8 (&b)[4],
                                        unsigned aA01, unsigned aA2,
                                        unsigned bB01, unsigned bB2) {
    const unsigned ad = (BUF < 2) ? aA01 : aA2;
    const unsigned bd = (BUF < 2) ? bB01 : bB2;
    constexpr int bo = (BUF < 2) ? BUF * 32768 : 0;
    DSRI(a[0], ad, bo + 0);
    DSRI(a[1], ad, bo + 1024);
    DSRI(a[2], ad, bo + 2048);
    DSRI(a[3], ad, bo + 3072);
    DSRI(b[0], bd, bo + 0);
    DSRI(b[1], bd, bo + 1024);
    DSRI(b[2], bd, bo + 2048);
    DSRI(b[3], bd, bo + 3072);
}

template <int BUF>
__device__ __forceinline__ void read_RB(bf16x8 (&a2)[4], unsigned aA01, unsigned aA2) {
    const unsigned ad = (BUF < 2) ? aA01 : aA2;
    constexpr int bo = (BUF < 2) ? BUF * 32768 : 0;
    DSRI(a2[0], ad, bo + 4096);
    DSRI(a2[1], ad, bo + 5120);
    DSRI(a2[2], ad, bo + 6144);
    DSRI(a2[3], ad, bo + 7168);
}

template <int MB>
__device__ __forceinline__ void mfma4(f32x4 (&acc)[8][4], const bf16x8 (&av)[4],
                                      const bf16x8 (&bv)[4]) {
    __builtin_amdgcn_s_setprio(1);
#pragma unroll
    for (int m = 0; m < 4; ++m)
#pragma unroll
        for (int n = 0; n < 4; ++n)
            acc[MB + m][n] = __builtin_amdgcn_mfma_f32_16x16x32_bf16(
                av[m], bv[n], acc[MB + m][n], 0, 0, 0);
    __builtin_amdgcn_s_setprio(0);
}

// stage one 16 KiB region (256 rows x 32 k) of K-tile t into buf DBUF.
template <int DBUF, int ISB>
__device__ __forceinline__ void stage2(const unsigned short* p0, const unsigned short* p1,
                                       int t, unsigned short* lds, int wLds) {
    const unsigned short* s0 = p0 + t * 32;
    const unsigned short* s1 = p1 + t * 32;
    unsigned short* d = lds + DBUF * 16384 + ISB * 8192 + wLds;
    gload_lds16(s0, d);
    gload_lds16(s1, d + 512);
}

// one K-tile: B=buf, BN=(B+1)%3, BS=(B+2)%3; CA_/CB_=consume color frags,
// NA_/NB_=next color frags; tt = tile being staged (= j+2).
#define PH_TILE(B, BN, BS, CA_, CB_, NA_, NB_, tt)                        \
    do {                                                                  \
        read_RB<B>(a2, aA01, aA2);                                        \
        stage2<BS, 0>(pA0, pA1, (tt), lds, wLds);                         \
        LGKM(4);                                                          \
        mfma4<0>(acc, CA_, CB_);                                          \
        asm volatile("s_waitcnt vmcnt(2)" ::: "memory");                  \
        BAR();                                                            \
        read_RA<BN>(NA_, NB_, aA01, aA2, bB01, bB2);                      \
        stage2<BS, 1>(pB0, pB1, (tt), lds, wLds);                         \
        LGKM(8);                                                          \
        mfma4<4>(acc, a2, CB_);                                           \
        BAR();                                                            \
    } while (0)

__global__ __launch_bounds__(512, 2)
void gemm_kernel(const unsigned short* __restrict__ A,
                 const unsigned short* __restrict__ BT,
                 const float* __restrict__ bias,
                 float* __restrict__ C) {
    __shared__ unsigned short lds[49152];   // 96 KiB: 3 bufs x 32 KiB

    constexpr int NT = N_DIM / 256;  // 43
    int wg = blockIdx.x, nwg = gridDim.x;
    int q = nwg >> 3, r = nwg & 7;
    int xcd = wg & 7, li = wg >> 3;
    int swz = (xcd < r ? xcd * (q + 1) : r * (q + 1) + (xcd - r) * q) + li;
    int by = swz / NT, bx = swz - by * NT;
    int brow = by << 8, bcol = bx << 8;

    int t = threadIdx.x;
    int lane = t & 63, w = t >> 6;
    int wr = w >> 2, wc = w & 3;           // 2 x 4 wave grid
    int fr = lane & 15, fq = lane >> 4;

    // T2 bank swizzle: read XOR on byte bits 4-5; source col perm on staging.
    const unsigned xr = (unsigned)((fr & 6) << 3);
    const int riw = lane >> 2;
    const int s8 = ((lane & 3) ^ ((lane >> 3) & 3)) << 3;
    const int w32 = w * 32, wLds = w * 1024;

    const unsigned ldsB = lds_addr(lds);
    const unsigned aA01 = ldsB + ((unsigned)((wr * 128 + fr) * 64 + fq * 16) ^ xr);
    const unsigned bB01 = ldsB + 16384u + ((unsigned)((wc * 64 + fr) * 64 + fq * 16) ^ xr);
    const unsigned aA2 = aA01 + 65536;
    const unsigned bB2 = bB01 + 65536;

    // staging source pointers (row slice fixed per thread; k via t*32)
    const unsigned short* pA0 = A + (int64_t)(brow + w32 + riw) * K_DIM + s8;
    const unsigned short* pA1 = pA0 + 16 * K_DIM;
    const unsigned short* pB0 = BT + (int64_t)(bcol + w32 + riw) * K_DIM + s8;
    const unsigned short* pB1 = pB0 + 16 * K_DIM;

    f32x4 acc[8][4];
#pragma unroll
    for (int m = 0; m < 8; ++m)
#pragma unroll
        for (int n = 0; n < 4; ++n) acc[m][n] = (f32x4){0.f, 0.f, 0.f, 0.f};

    bf16x8 aX[4], bX[4], aY[4], bY[4], a2[4];

    // ---- prologue: stage tiles 0,1 into bufs 0,1 (8 loads); confirm buf0;
    // pre-issue RA_0 (color X). Leaves {A1,B1} outstanding = induction state.
    stage2<0, 0>(pA0, pA1, 0, lds, wLds);
    stage2<0, 1>(pB0, pB1, 0, lds, wLds);
    stage2<1, 0>(pA0, pA1, 1, lds, wLds);
    stage2<1, 1>(pB0, pB1, 1, lds, wLds);
    asm volatile("s_waitcnt vmcnt(4)" ::: "memory");
    BAR();
    read_RA<0>(aX, bX, aA01, aA2, bB01, bB2);

#pragma unroll 1
    for (int body = 0; body < 21; ++body) {
        const int t2 = body * 6 + 2;
        PH_TILE(0, 1, 2, aX, bX, aY, bY, t2);       // tile 6b+0
        PH_TILE(1, 2, 0, aY, bY, aX, bX, t2 + 1);   // tile 6b+1
        PH_TILE(2, 0, 1, aX, bX, aY, bY, t2 + 2);   // tile 6b+2
        PH_TILE(0, 1, 2, aY, bY, aX, bX, t2 + 3);   // tile 6b+3
        PH_TILE(1, 2, 0, aX, bX, aY, bY, t2 + 4);   // tile 6b+4
        PH_TILE(2, 0, 1, aY, bY, aX, bX, t2 + 5);   // tile 6b+5
    }

    // ---- tail: tiles 126 (buf0, color X) and 127 (buf1, color Y), no stages.
    read_RB<0>(a2, aA01, aA2);
    LGKM(4);
    mfma4<0>(acc, aX, bX);
    asm volatile("s_waitcnt vmcnt(0)" ::: "memory");   // drain A_127,B_127
    BAR();
    read_RA<1>(aY, bY, aA01, aA2, bB01, bB2);
    LGKM(8);
    mfma4<4>(acc, a2, bX);
    BAR();
    read_RB<1>(a2, aA01, aA2);
    LGKM(4);
    mfma4<0>(acc, aY, bY);
    LGKM(0);
    mfma4<4>(acc, a2, bY);

    // ---- epilogue: C/D layout col=lane&15, row=(lane>>4)*4+reg ----
    int orow0 = brow + wr * 128 + fq * 4;
    int ocol0 = bcol + wc * 64 + fr;
#pragma unroll
    for (int n = 0; n < 4; ++n) {
        int col = ocol0 + n * 16;
        float bval = bias[col];
#pragma unroll
        for (int m = 0; m < 8; ++m) {
            int row = orow0 + m * 16;
            float* cp = C + (int64_t)row * N_DIM + col;
#pragma unroll
            for (int j = 0; j < 4; ++j) {
                cp[(int64_t)j * N_DIM] = acc[m][n][j] + bval;
            }
        }
    }
}

extern "C" void kernel_launch(void* const* d_in, const int* in_sizes, int n_in,
                              void* d_out, int out_size, void* d_ws, size_t ws_size,
                              hipStream_t stream) {
    const float* x      = (const float*)d_in[0];
    const int* ci       = (const int*)d_in[1];
    const int* wp       = (const int*)d_in[2];
    const float* scales = (const float*)d_in[3];
    const float* bias   = (const float*)d_in[4];
    float* out          = (float*)d_out;

    const size_t wT_bytes = (size_t)N_DIM * K_DIM * 2;
    unsigned short* wT = (unsigned short*)d_ws;
    unsigned short* xg = wT + (size_t)N_DIM * K_DIM;

    size_t cap = (ws_size > wT_bytes) ? (ws_size - wT_bytes) : 0;
    int max_rows = (int)(cap / ((size_t)K_DIM * 2));
    int chunk_rows = (max_rows / 256) * 256;
    if (chunk_rows <= 0) chunk_rows = 256;      // best effort
    if (chunk_rows > M_DIM) chunk_rows = M_DIM;

    dequant_w_kernel<<<dim3(N_DIM / 64, K_DIM / 64), 256, 0, stream>>>(wp, scales, wT);

    for (int m0 = 0; m0 < M_DIM; m0 += chunk_rows) {
        int rows = M_DIM - m0 < chunk_rows ? M_DIM - m0 : chunk_rows;
        int pgrid = (int)(((int64_t)rows * K_DIM) / (4 * 256));
        permute_x_kernel<<<pgrid, 256, 0, stream>>>(
            x + (int64_t)m0 * K_DIM, ci, xg);
        int grid = (rows / 256) * (N_DIM / 256);
        gemm_kernel<<<grid, 512, 0, stream>>>(
            xg, wT, bias, out + (int64_t)m0 * N_DIM);
    }
}